// Round 6
// baseline (2833.797 us; speedup 1.0000x reference)
//
#include <hip/hip_runtime.h>

// SimpleRNN: x(256,2048,8) f32, h(1,256,128), W_ih(128,8), W_hh(128,128),
// b_ih(128), b_hh(128), W_head(1,128), b_head(1)
// out = [pred(256) | last_step_features(256,128) | h_n(256,128)]  (f32)
//
// R4 design: ONE WAVE PER BATCH ROW. 256 blocks x 64 threads, 1 wave/CU.
// Lane l owns outputs j0=2l, j1=2l+1; holds W_hh rows j0,j1 interleaved as
// 128 f32x2 (256 VGPRs; budget is 512 at launch_bounds(64,1)).
// h lives in per-wave LDS, read as wave-uniform broadcasts; single-wave
// lockstep makes read->write ordering implicit: NO barriers in the loop.
// Dot via v_pk_fma_f32 with op_sel scalar-broadcast of h (no splat movs).

typedef float f32x2 __attribute__((ext_vector_type(2)));
typedef float f32x4 __attribute__((ext_vector_type(4)));

#define BB 256
#define TT 2048
#define II 8
#define HH 128

// broadcast LOW half of src0 pair to both output halves
#define PK_FMA_LO(acc, hp, wp) \
    asm("v_pk_fma_f32 %0, %1, %2, %0 op_sel:[0,0,0] op_sel_hi:[0,1,1]" \
        : "+v"(acc) : "v"(hp), "v"(wp))
// broadcast HIGH half of src0 pair to both output halves
#define PK_FMA_HI(acc, hp, wp) \
    asm("v_pk_fma_f32 %0, %1, %2, %0 op_sel:[1,0,0] op_sel_hi:[1,1,1]" \
        : "+v"(acc) : "v"(hp), "v"(wp))
#define PK_MUL_LO(dst, hp, wp) \
    asm("v_pk_mul_f32 %0, %1, %2 op_sel:[0,0] op_sel_hi:[0,1]" \
        : "=v"(dst) : "v"(hp), "v"(wp))
#define PK_MUL_HI(dst, hp, wp) \
    asm("v_pk_mul_f32 %0, %1, %2 op_sel:[1,0] op_sel_hi:[1,1]" \
        : "=v"(dst) : "v"(hp), "v"(wp))
#define PK_FMA3_LO(dst, hp, wp, c) \
    asm("v_pk_fma_f32 %0, %1, %2, %3 op_sel:[0,0,0] op_sel_hi:[0,1,1]" \
        : "=v"(dst) : "v"(hp), "v"(wp), "v"(c))

__launch_bounds__(64, 1)
__global__ void rnn_wave_kernel(const float* __restrict__ x,
                                const float* __restrict__ h0,
                                const float* __restrict__ W_ih,
                                const float* __restrict__ W_hh,
                                const float* __restrict__ b_ih,
                                const float* __restrict__ b_hh,
                                const float* __restrict__ W_head,
                                const float* __restrict__ b_head,
                                float* __restrict__ out)
{
    __shared__ __align__(16) float h_s[HH];          // hidden state (this wave only)
    __shared__ __align__(16) float x_s[2][16 * II];  // 2 x 16-step x stage

    const int b  = blockIdx.x;       // batch row
    const int l  = threadIdx.x;      // lane 0..63
    const int j0 = 2 * l;            // this lane's two outputs: j0, j0+1

    // ---- load & interleave W_hh rows j0, j0+1: w2[k] = (W[j0][k], W[j1][k]) ----
    f32x2 w2[HH];
    {
        const f32x4* rA = (const f32x4*)(W_hh + (size_t)j0 * HH);
        const f32x4* rB = (const f32x4*)(W_hh + (size_t)(j0 + 1) * HH);
        #pragma unroll
        for (int q = 0; q < 32; ++q) {
            const f32x4 a = rA[q], c = rB[q];
            w2[4 * q + 0] = (f32x2){a.x, c.x};
            w2[4 * q + 1] = (f32x2){a.y, c.y};
            w2[4 * q + 2] = (f32x2){a.z, c.z};
            w2[4 * q + 3] = (f32x2){a.w, c.w};
        }
    }
    f32x2 wih[II];
    {
        const f32x4* rA = (const f32x4*)(W_ih + j0 * II);
        const f32x4* rB = (const f32x4*)(W_ih + (j0 + 1) * II);
        #pragma unroll
        for (int q = 0; q < 2; ++q) {
            const f32x4 a = rA[q], c = rB[q];
            wih[4 * q + 0] = (f32x2){a.x, c.x};
            wih[4 * q + 1] = (f32x2){a.y, c.y};
            wih[4 * q + 2] = (f32x2){a.z, c.z};
            wih[4 * q + 3] = (f32x2){a.w, c.w};
        }
    }
    f32x2 bias2 = (f32x2){b_ih[j0] + b_hh[j0], b_ih[j0 + 1] + b_hh[j0 + 1]};

    // opaque pin: asm-volatile defs cannot be rematerialized or sunk
    #pragma unroll
    for (int k = 0; k < HH; ++k) asm volatile("" : "+v"(w2[k]));
    #pragma unroll
    for (int i = 0; i < II; ++i) asm volatile("" : "+v"(wih[i]));
    asm volatile("" : "+v"(bias2));

    const float* xg = x + (size_t)b * TT * II;

    // init h and first x chunk (single wave: lockstep ordering, no barrier)
    *(f32x2*)&h_s[j0]      = *(const f32x2*)&h0[b * HH + j0];
    *(f32x2*)&x_s[0][2 * l] = *(const f32x2*)&xg[2 * l];

    f32x2 xpre = (f32x2){0.0f, 0.0f};
    f32x2 hn2  = (f32x2){0.0f, 0.0f};

    for (int t = 0; t < TT; ++t) {
        const int tin = t & 15;
        const int buf = (t >> 4) & 1;

        if (tin == 0) {                      // prefetch next 16-step x chunk
            const int tn = t + 16;
            xpre = (tn < TT) ? *(const f32x2*)&xg[tn * II + 2 * l]
                             : (f32x2){0.0f, 0.0f};
        }

        // ---- x-projection (wave-uniform broadcasts from LDS) ----
        const float* xr = &x_s[buf][tin * II];
        const f32x2 xp0 = *(const f32x2*)&xr[0];
        const f32x2 xp1 = *(const f32x2*)&xr[2];
        const f32x2 xp2 = *(const f32x2*)&xr[4];
        const f32x2 xp3 = *(const f32x2*)&xr[6];
        f32x2 a0, a1, a2, a3;
        PK_FMA3_LO(a0, xp0, wih[0], bias2);
        PK_MUL_HI (a1, xp0, wih[1]);
        PK_MUL_LO (a2, xp1, wih[2]);
        PK_MUL_HI (a3, xp1, wih[3]);
        PK_FMA_LO (a0, xp2, wih[4]);
        PK_FMA_HI (a1, xp2, wih[5]);
        PK_FMA_LO (a2, xp3, wih[6]);
        PK_FMA_HI (a3, xp3, wih[7]);

        // ---- h dot: 64 broadcast pairs, 128 pk_fma (op_sel h-scalar bcast) ----
        #pragma unroll
        for (int kp = 0; kp < 64; ++kp) {
            const f32x2 hp = *(const f32x2*)&h_s[2 * kp];
            if ((kp & 1) == 0) {
                PK_FMA_LO(a0, hp, w2[2 * kp]);
                PK_FMA_HI(a1, hp, w2[2 * kp + 1]);
            } else {
                PK_FMA_LO(a2, hp, w2[2 * kp]);
                PK_FMA_HI(a3, hp, w2[2 * kp + 1]);
            }
        }
        const f32x2 s2 = (a0 + a1) + (a2 + a3);   // 3x v_pk_add_f32

        // ---- tanh both outputs ----
        const float e0 = __builtin_amdgcn_exp2f(s2.x * 2.8853900817779268f);
        const float e1 = __builtin_amdgcn_exp2f(s2.y * 2.8853900817779268f);
        hn2.x = 1.0f - 2.0f * __builtin_amdgcn_rcpf(e0 + 1.0f);
        hn2.y = 1.0f - 2.0f * __builtin_amdgcn_rcpf(e1 + 1.0f);

        // all lanes' reads above happened before this write (wave lockstep)
        *(f32x2*)&h_s[j0] = hn2;

        if (tin == 15) *(f32x2*)&x_s[buf ^ 1][2 * l] = xpre;
    }

    // ---- epilogue ----
    *(f32x2*)&out[BB + b * HH + j0]           = hn2;   // last_step_features
    *(f32x2*)&out[BB + BB * HH + b * HH + j0] = hn2;   // h_n
    const f32x2 wh = (f32x2){W_head[j0], W_head[j0 + 1]};
    const f32x2 p2 = (f32x2){hn2.x * wh.x, hn2.y * wh.y};
    float p = p2.x + p2.y;
    #pragma unroll
    for (int off = 32; off > 0; off >>= 1) p += __shfl_down(p, off);
    if (l == 0) out[b] = p + b_head[0];
}

extern "C" void kernel_launch(void* const* d_in, const int* in_sizes, int n_in,
                              void* d_out, int out_size, void* d_ws, size_t ws_size,
                              hipStream_t stream) {
    const float* x      = (const float*)d_in[0];
    const float* h0     = (const float*)d_in[1];
    const float* W_ih   = (const float*)d_in[2];
    const float* W_hh   = (const float*)d_in[3];
    const float* b_ih   = (const float*)d_in[4];
    const float* b_hh   = (const float*)d_in[5];
    const float* W_head = (const float*)d_in[6];
    const float* b_head = (const float*)d_in[7];
    float* out = (float*)d_out;

    hipLaunchKernelGGL(rnn_wave_kernel, dim3(BB), dim3(64), 0, stream,
                       x, h0, W_ih, W_hh, b_ih, b_hh, W_head, b_head, out);
}

// Round 7
// 891.163 us; speedup vs baseline: 3.1799x; 3.1799x over previous
//
#include <hip/hip_runtime.h>

// SimpleRNN via MFMA over the batch dimension.
// x(256,2048,8) f32, h0(256,128), W_ih(128,8), W_hh(128,128), b_ih/b_hh(128),
// W_head(128), b_head(1). out = [pred(256) | feats(256,128) | h_n(256,128)] f32.
//
// 16 blocks x 512 threads (8 waves). Block owns 16 batch rows.
// Per step t: pre(16x128) = h(16x128) @ W_hh^T + x_t(16x8) @ W_ih^T + bias,
// computed as fp16 MFMA 16x16x32: wave w = N-tile (cols 16w..16w+15).
// B-frags (W_hh^T, W_ih^T) resident in 20 VGPRs/lane. h tile double-buffered
// in LDS fp16 [2][16][136] (pad->conflict-free b128 A-frag reads).
// Raw s_barrier + lgkmcnt(0) only => depth-4 x-prefetch floats across
// barriers (no vmcnt drain). Accumulation fp32 (MFMA C), tanh fp32.

typedef _Float16 half8 __attribute__((ext_vector_type(8)));
typedef float f32x4 __attribute__((ext_vector_type(4)));

#define BB 256
#define TT 2048
#define II 8
#define HH 128
#define RB 16            // batch rows per block
#define NBLK (BB / RB)   // 16 blocks
#define LDH (HH + 8)     // padded LDS row: 136 halves = 272 B

__device__ __forceinline__ float quad_sum(float x) {
    int xi = __builtin_bit_cast(int, x);
    int y1 = __builtin_amdgcn_update_dpp(0, xi, 0xB1, 0xF, 0xF, true); // xor1
    float s1 = x + __builtin_bit_cast(float, y1);
    int s1i = __builtin_bit_cast(int, s1);
    int y2 = __builtin_amdgcn_update_dpp(0, s1i, 0x4E, 0xF, 0xF, true); // xor2
    return s1 + __builtin_bit_cast(float, y2);
}

__launch_bounds__(512, 1)
__global__ void rnn_mfma_kernel(const float* __restrict__ x,
                                const float* __restrict__ h0,
                                const float* __restrict__ W_ih,
                                const float* __restrict__ W_hh,
                                const float* __restrict__ b_ih,
                                const float* __restrict__ b_hh,
                                const float* __restrict__ W_head,
                                const float* __restrict__ b_head,
                                float* __restrict__ out)
{
    __shared__ _Float16 hT[2][RB][LDH];   // double-buffered fp16 hidden tile
    __shared__ float    hf[RB][HH + 1];   // final f32 h for pred reduction

    const int tid = threadIdx.x;
    const int w   = tid >> 6;       // wave 0..7 = N-tile index
    const int l   = tid & 63;
    const int lm  = l & 15;         // A-row (batch) / B,C-col (output j)
    const int lg  = l >> 4;         // k-group 0..3
    const int j   = w * 16 + lm;    // this lane's output column
    const int b0  = blockIdx.x * RB;

    // ---- resident B fragments ----
    // B_hh[k][j] = W_hh[j][k]; lane holds k = 32m + lg*8 + i (contiguous row read)
    half8 bhh[4];
    #pragma unroll
    for (int m = 0; m < 4; ++m) {
        const float* p = W_hh + (size_t)j * HH + 32 * m + lg * 8;
        #pragma unroll
        for (int i = 0; i < 8; ++i) bhh[m][i] = (_Float16)p[i];
    }
    // B_ih[k][j] = W_ih[j][k] for k<8 (lg==0), zero for k>=8 -> garbage-A killed
    half8 bih;
    #pragma unroll
    for (int i = 0; i < 8; ++i)
        bih[i] = (_Float16)((lg == 0) ? W_ih[j * II + i] : 0.0f);

    const float bv = b_ih[j] + b_hh[j];
    f32x4 bias4 = {bv, bv, bv, bv};
    f32x4 zero4 = {0.f, 0.f, 0.f, 0.f};

    // pin resident frags (cheap insurance vs rematerialization)
    asm volatile("" : "+v"(bhh[0]), "+v"(bhh[1]), "+v"(bhh[2]), "+v"(bhh[3]), "+v"(bih));

    // ---- init h tile (fp16) ----
    #pragma unroll
    for (int e = 0; e < 4; ++e) {
        const int idx = tid * 4 + e;           // 0..2047
        const int r = idx >> 7, c = idx & 127;
        hT[0][r][c] = (_Float16)h0[(b0 + r) * HH + c];
    }
    __syncthreads();

    // ---- x prefetch pipeline, depth 4 (all lanes load row lm; redundant
    // across lg groups but coalesced & off critical path) ----
    const float* xb = x + (size_t)(b0 + lm) * TT * II;
    f32x4 xa0 = *(const f32x4*)(xb + 0 * II), xv0 = *(const f32x4*)(xb + 0 * II + 4);
    f32x4 xa1 = *(const f32x4*)(xb + 1 * II), xv1 = *(const f32x4*)(xb + 1 * II + 4);
    f32x4 xa2 = *(const f32x4*)(xb + 2 * II), xv2 = *(const f32x4*)(xb + 2 * II + 4);
    f32x4 xa3 = *(const f32x4*)(xb + 3 * II), xv3 = *(const f32x4*)(xb + 3 * II + 4);

    float hfin[4] = {0.f, 0.f, 0.f, 0.f};

    // step T: reads hT[T&1], writes hT[(T+1)&1]; refills its x regs with T+4
    #define STEP(T, RBUF, XA, XV)                                               \
    {                                                                           \
        half8 a0 = *(const half8*)&hT[RBUF][lm][ 0 + lg * 8];                   \
        half8 a1 = *(const half8*)&hT[RBUF][lm][32 + lg * 8];                   \
        half8 a2 = *(const half8*)&hT[RBUF][lm][64 + lg * 8];                   \
        half8 a3 = *(const half8*)&hT[RBUF][lm][96 + lg * 8];                   \
        half8 ax;                                                               \
        ax[0] = (_Float16)XA.x; ax[1] = (_Float16)XA.y;                         \
        ax[2] = (_Float16)XA.z; ax[3] = (_Float16)XA.w;                         \
        ax[4] = (_Float16)XV.x; ax[5] = (_Float16)XV.y;                         \
        ax[6] = (_Float16)XV.z; ax[7] = (_Float16)XV.w;                         \
        f32x4 cA = __builtin_amdgcn_mfma_f32_16x16x32_f16(ax, bih, bias4, 0, 0, 0); \
        cA = __builtin_amdgcn_mfma_f32_16x16x32_f16(a0, bhh[0], cA, 0, 0, 0);   \
        cA = __builtin_amdgcn_mfma_f32_16x16x32_f16(a1, bhh[1], cA, 0, 0, 0);   \
        f32x4 cB = __builtin_amdgcn_mfma_f32_16x16x32_f16(a2, bhh[2], zero4, 0, 0, 0); \
        cB = __builtin_amdgcn_mfma_f32_16x16x32_f16(a3, bhh[3], cB, 0, 0, 0);   \
        _Pragma("unroll")                                                       \
        for (int r = 0; r < 4; ++r) {                                           \
            const float s  = cA[r] + cB[r];                                     \
            const float e2 = __builtin_amdgcn_exp2f(s * 2.8853900817779268f);   \
            const float hv = 1.0f - 2.0f * __builtin_amdgcn_rcpf(e2 + 1.0f);    \
            hfin[r] = hv;                                                       \
            hT[(RBUF) ^ 1][lg * 4 + r][j] = (_Float16)hv;                       \
        }                                                                       \
        { int tn = (T) + 4; if (tn > TT - 1) tn = TT - 1;                       \
          XA = *(const f32x4*)(xb + (size_t)tn * II);                           \
          XV = *(const f32x4*)(xb + (size_t)tn * II + 4); }                     \
        asm volatile("s_waitcnt lgkmcnt(0)\n\ts_barrier" ::: "memory");         \
    }

    for (int t = 0; t < TT; t += 4) {
        STEP(t + 0, 0, xa0, xv0)
        STEP(t + 1, 1, xa1, xv1)
        STEP(t + 2, 0, xa2, xv2)
        STEP(t + 3, 1, xa3, xv3)
    }
    #undef STEP

    // ---- epilogue: lane holds f32 h for rows lg*4+r, col j ----
    #pragma unroll
    for (int r = 0; r < 4; ++r) {
        const int row = b0 + lg * 4 + r;
        out[BB + row * HH + j]           = hfin[r];   // last_step_features
        out[BB + BB * HH + row * HH + j] = hfin[r];   // h_n
        hf[lg * 4 + r][j] = hfin[r];
    }
    __syncthreads();
    if (w == 0) {
        const int row = l >> 2;          // 16 rows, 4 lanes each
        const int kq  = (l & 3) * 32;    // 32 cols per lane
        float s = 0.f;
        for (int q = 0; q < 32; ++q) s = fmaf(hf[row][kq + q], W_head[kq + q], s);
        s = quad_sum(s);
        if ((l & 3) == 0) out[b0 + row] = s + b_head[0];
    }
}

extern "C" void kernel_launch(void* const* d_in, const int* in_sizes, int n_in,
                              void* d_out, int out_size, void* d_ws, size_t ws_size,
                              hipStream_t stream) {
    const float* x      = (const float*)d_in[0];
    const float* h0     = (const float*)d_in[1];
    const float* W_ih   = (const float*)d_in[2];
    const float* W_hh   = (const float*)d_in[3];
    const float* b_ih   = (const float*)d_in[4];
    const float* b_hh   = (const float*)d_in[5];
    const float* W_head = (const float*)d_in[6];
    const float* b_head = (const float*)d_in[7];
    float* out = (float*)d_out;

    hipLaunchKernelGGL(rnn_mfma_kernel, dim3(NBLK), dim3(512), 0, stream,
                       x, h0, W_ih, W_hh, b_ih, b_hh, W_head, b_head, out);
}

// Round 8
// 735.626 us; speedup vs baseline: 3.8522x; 1.2114x over previous
//
#include <hip/hip_runtime.h>

// SimpleRNN via MFMA, operand-swapped: per step compute
//   pre^T(128x16) = W_hh(128x128) @ h^T(128x16) + W_ih @ x_t^T + bias
// A = W_hh rows (M=j), B = h^T (N=batch). C lane layout: row=j (4lg+r),
// col=batch (lm)  =>  each lane's 4 outputs are 4 CONSECUTIVE j for one
// batch column -> single packed ds_write_b64 (R5's 4.2M bank conflicts came
// from the column-scattered b16 writes of the unswapped layout).
// 16 blocks x 256 threads (4 waves); wave w owns j in [32w, 32w+32) (2 tiles).
// W_hh A-frags resident: 8 x half8 = 32 VGPR/lane. h tile double-buffered
// fp16 LDS [2][16][136]. Raw s_barrier + lgkmcnt(0) only (x-prefetch floats).

typedef _Float16 half8 __attribute__((ext_vector_type(8)));
typedef _Float16 half4 __attribute__((ext_vector_type(4)));
typedef float f32x4 __attribute__((ext_vector_type(4)));

#define BB 256
#define TT 2048
#define II 8
#define HH 128
#define RB 16            // batch rows per block
#define NBLK (BB / RB)   // 16 blocks
#define LDH 136          // padded LDS row (halves): 272 B
#define THREADS 256      // 4 waves

__launch_bounds__(THREADS, 1)
__global__ void rnn_mfma2_kernel(const float* __restrict__ x,
                                 const float* __restrict__ h0,
                                 const float* __restrict__ W_ih,
                                 const float* __restrict__ W_hh,
                                 const float* __restrict__ b_ih,
                                 const float* __restrict__ b_hh,
                                 const float* __restrict__ W_head,
                                 const float* __restrict__ b_head,
                                 float* __restrict__ out)
{
    __shared__ _Float16 hT[2][RB][LDH];   // double-buffered fp16 h tile
    __shared__ float predpart[4][RB];

    const int tid = threadIdx.x;
    const int w   = tid >> 6;        // wave 0..3
    const int l   = tid & 63;
    const int lm  = l & 15;          // B col = batch row; A row = j-within-tile
    const int lg  = l >> 4;          // k-group 0..3
    const int b0  = blockIdx.x * RB;
    const int jb  = w * 32;          // wave's j base (2 tiles of 16)

    // ---- resident A-frags: W_hh[j=jb+16*tile+lm][k=32*kb+8*lg+i] ----
    half8 whh[2][4];
    #pragma unroll
    for (int tile = 0; tile < 2; ++tile)
        #pragma unroll
        for (int kb = 0; kb < 4; ++kb) {
            const float* p = W_hh + (size_t)(jb + 16 * tile + lm) * HH + 32 * kb + 8 * lg;
            #pragma unroll
            for (int i = 0; i < 8; ++i) whh[tile][kb][i] = (_Float16)p[i];
        }
    // W_ih A-frag, K-padded: rows j, k=i<8 only (lg==0); zeros kill B garbage
    half8 wih[2];
    #pragma unroll
    for (int tile = 0; tile < 2; ++tile)
        #pragma unroll
        for (int i = 0; i < 8; ++i)
            wih[tile][i] = (_Float16)((lg == 0) ? W_ih[(jb + 16 * tile + lm) * II + i] : 0.0f);
    // bias as C-init: bias4[tile][r] for j = jb+16*tile+4*lg+r
    f32x4 bias4[2];
    #pragma unroll
    for (int tile = 0; tile < 2; ++tile)
        #pragma unroll
        for (int r = 0; r < 4; ++r) {
            const int j = jb + 16 * tile + 4 * lg + r;
            bias4[tile][r] = b_ih[j] + b_hh[j];
        }
    const f32x4 zero4 = {0.f, 0.f, 0.f, 0.f};

    asm volatile("" : "+v"(whh[0][0]), "+v"(whh[0][1]), "+v"(whh[0][2]), "+v"(whh[0][3]),
                      "+v"(whh[1][0]), "+v"(whh[1][1]), "+v"(whh[1][2]), "+v"(whh[1][3]),
                      "+v"(wih[0]), "+v"(wih[1]));

    // ---- init h tile: thread covers 8 consecutive halves of row tid>>4 ----
    {
        const int r = tid >> 4, c = (tid & 15) * 8;
        const float* hp = h0 + (size_t)(b0 + r) * HH + c;
        half8 hv;
        #pragma unroll
        for (int i = 0; i < 8; ++i) hv[i] = (_Float16)hp[i];
        *(half8*)&hT[0][r][c] = hv;
    }
    __syncthreads();

    // ---- x prefetch pipeline, depth 4 (lane loads batch row lm) ----
    const float* xb = x + (size_t)(b0 + lm) * TT * II;
    f32x4 xa0 = *(const f32x4*)(xb + 0 * II), xv0 = *(const f32x4*)(xb + 0 * II + 4);
    f32x4 xa1 = *(const f32x4*)(xb + 1 * II), xv1 = *(const f32x4*)(xb + 1 * II + 4);
    f32x4 xa2 = *(const f32x4*)(xb + 2 * II), xv2 = *(const f32x4*)(xb + 2 * II + 4);
    f32x4 xa3 = *(const f32x4*)(xb + 3 * II), xv3 = *(const f32x4*)(xb + 3 * II + 4);

    float hfin[2][4];

    #define STEP(T, RBUF, XA, XV)                                                \
    {                                                                            \
        /* B h-frags: h[m=lm][k=32kb+8lg..+7], shared by both tiles */           \
        half8 bh0 = *(const half8*)&hT[RBUF][lm][ 0 + 8 * lg];                   \
        half8 bh1 = *(const half8*)&hT[RBUF][lm][32 + 8 * lg];                   \
        half8 bh2 = *(const half8*)&hT[RBUF][lm][64 + 8 * lg];                   \
        half8 bh3 = *(const half8*)&hT[RBUF][lm][96 + 8 * lg];                   \
        /* x B-frag: garbage for lg>0 is killed by wih zeros on A side */        \
        half8 bx;                                                                \
        bx[0] = (_Float16)XA.x; bx[1] = (_Float16)XA.y;                          \
        bx[2] = (_Float16)XA.z; bx[3] = (_Float16)XA.w;                          \
        bx[4] = (_Float16)XV.x; bx[5] = (_Float16)XV.y;                          \
        bx[6] = (_Float16)XV.z; bx[7] = (_Float16)XV.w;                          \
        /* 10 MFMAs, 4 parallel chains (<=3 deep) */                             \
        f32x4 c0A = __builtin_amdgcn_mfma_f32_16x16x32_f16(wih[0], bx, bias4[0], 0, 0, 0); \
        f32x4 c1A = __builtin_amdgcn_mfma_f32_16x16x32_f16(wih[1], bx, bias4[1], 0, 0, 0); \
        f32x4 c0B = __builtin_amdgcn_mfma_f32_16x16x32_f16(whh[0][1], bh1, zero4, 0, 0, 0); \
        f32x4 c1B = __builtin_amdgcn_mfma_f32_16x16x32_f16(whh[1][1], bh1, zero4, 0, 0, 0); \
        c0A = __builtin_amdgcn_mfma_f32_16x16x32_f16(whh[0][0], bh0, c0A, 0, 0, 0); \
        c1A = __builtin_amdgcn_mfma_f32_16x16x32_f16(whh[1][0], bh0, c1A, 0, 0, 0); \
        c0B = __builtin_amdgcn_mfma_f32_16x16x32_f16(whh[0][3], bh3, c0B, 0, 0, 0); \
        c1B = __builtin_amdgcn_mfma_f32_16x16x32_f16(whh[1][3], bh3, c1B, 0, 0, 0); \
        c0A = __builtin_amdgcn_mfma_f32_16x16x32_f16(whh[0][2], bh2, c0A, 0, 0, 0); \
        c1A = __builtin_amdgcn_mfma_f32_16x16x32_f16(whh[1][2], bh2, c1A, 0, 0, 0); \
        const f32x4 s0 = c0A + c0B;                                              \
        const f32x4 s1 = c1A + c1B;                                              \
        _Pragma("unroll")                                                        \
        for (int r = 0; r < 4; ++r) {                                            \
            const float e0 = __builtin_amdgcn_exp2f(s0[r] * 2.8853900817779268f);\
            hfin[0][r] = 1.0f - 2.0f * __builtin_amdgcn_rcpf(e0 + 1.0f);         \
            const float e1 = __builtin_amdgcn_exp2f(s1[r] * 2.8853900817779268f);\
            hfin[1][r] = 1.0f - 2.0f * __builtin_amdgcn_rcpf(e1 + 1.0f);         \
        }                                                                        \
        /* packed b64 writes: 4 consecutive j for batch col lm */                \
        half4 hw0 = {(_Float16)hfin[0][0], (_Float16)hfin[0][1],                 \
                     (_Float16)hfin[0][2], (_Float16)hfin[0][3]};                \
        half4 hw1 = {(_Float16)hfin[1][0], (_Float16)hfin[1][1],                 \
                     (_Float16)hfin[1][2], (_Float16)hfin[1][3]};                \
        *(half4*)&hT[(RBUF) ^ 1][lm][jb +      4 * lg] = hw0;                    \
        *(half4*)&hT[(RBUF) ^ 1][lm][jb + 16 + 4 * lg] = hw1;                    \
        { int tn = (T) + 4; if (tn > TT - 1) tn = TT - 1;                        \
          XA = *(const f32x4*)(xb + (size_t)tn * II);                            \
          XV = *(const f32x4*)(xb + (size_t)tn * II + 4); }                      \
        asm volatile("s_waitcnt lgkmcnt(0)\n\ts_barrier" ::: "memory");          \
    }

    for (int t = 0; t < TT; t += 4) {
        STEP(t + 0, 0, xa0, xv0)
        STEP(t + 1, 1, xa1, xv1)
        STEP(t + 2, 0, xa2, xv2)
        STEP(t + 3, 1, xa3, xv3)
    }
    #undef STEP

    // ---- epilogue: lane holds h_final[j=jb+16*tile+4lg+r][m=lm] ----
    float pp = 0.0f;
    #pragma unroll
    for (int tile = 0; tile < 2; ++tile)
        #pragma unroll
        for (int r = 0; r < 4; ++r) {
            const int j = jb + 16 * tile + 4 * lg + r;
            const int row = b0 + lm;
            const float hv = hfin[tile][r];
            out[BB + (size_t)row * HH + j]           = hv;   // last_step_features
            out[BB + BB * HH + (size_t)row * HH + j] = hv;   // h_n
            pp = fmaf(hv, W_head[j], pp);
        }
    // reduce over lg (lanes lm, lm+16, lm+32, lm+48)
    pp += __shfl_xor(pp, 16, 64);
    pp += __shfl_xor(pp, 32, 64);
    if (lg == 0) predpart[w][lm] = pp;
    __syncthreads();
    if (w == 0 && l < RB) {
        const float p = predpart[0][l] + predpart[1][l] + predpart[2][l] + predpart[3][l];
        out[b0 + l] = p + b_head[0];
    }
}

extern "C" void kernel_launch(void* const* d_in, const int* in_sizes, int n_in,
                              void* d_out, int out_size, void* d_ws, size_t ws_size,
                              hipStream_t stream) {
    const float* x      = (const float*)d_in[0];
    const float* h0     = (const float*)d_in[1];
    const float* W_ih   = (const float*)d_in[2];
    const float* W_hh   = (const float*)d_in[3];
    const float* b_ih   = (const float*)d_in[4];
    const float* b_hh   = (const float*)d_in[5];
    const float* W_head = (const float*)d_in[6];
    const float* b_head = (const float*)d_in[7];
    float* out = (float*)d_out;

    hipLaunchKernelGGL(rnn_mfma2_kernel, dim3(NBLK), dim3(THREADS), 0, stream,
                       x, h0, W_ih, W_hh, b_ih, b_hh, W_head, b_head, out);
}